// Round 1
// baseline (1159.276 us; speedup 1.0000x reference)
//
#include <hip/hip_runtime.h>

// MissHitScatter: PATH_NUM=4, IS_HIT=true -> out[0] = inputs, out[1..3] = 0.
// inputs: [65536, 1024] fp32; out: [4, 65536, 1024] fp32.
// Pure HBM-bound copy+zero: read 256 MiB, write 1 GiB.

__global__ __launch_bounds__(256) void MissHitScatter_kernel(
    const float4* __restrict__ in, float4* __restrict__ out,
    unsigned int n_vec_in, unsigned int n_vec_out) {
  unsigned int i = blockIdx.x * blockDim.x + threadIdx.x;
  if (i >= n_vec_out) return;
  float4 v;
  if (i < n_vec_in) {
    v = in[i];           // path-0 region: copy input
  } else {
    v.x = 0.0f; v.y = 0.0f; v.z = 0.0f; v.w = 0.0f;  // other paths: zero
  }
  out[i] = v;
}

extern "C" void kernel_launch(void* const* d_in, const int* in_sizes, int n_in,
                              void* d_out, int out_size, void* d_ws, size_t ws_size,
                              hipStream_t stream) {
  const float4* in = (const float4*)d_in[0];
  float4* out = (float4*)d_out;

  // in_sizes[0] = 65536*1024 = 67,108,864 floats; out_size = 4x that.
  unsigned int n_vec_in  = (unsigned int)(in_sizes[0] / 4);
  unsigned int n_vec_out = (unsigned int)(out_size / 4);

  const int block = 256;
  unsigned int grid = (n_vec_out + block - 1) / block;

  MissHitScatter_kernel<<<grid, block, 0, stream>>>(in, out, n_vec_in, n_vec_out);
}